// Round 1
// 471.283 us; speedup vs baseline: 1.0246x; 1.0246x over previous
//
#include <hip/hip_runtime.h>
#include <hip/hip_bf16.h>
#include <cstdint>

// ---------------------------------------------------------------------------
// BitLinear GLU: x[8192,2048] f32, W[8192,2048] f32 -> out[8192,4096] f32
//   Identity: out = (normed @ w_bin^T) * w_gamma  -- input_gamma cancels
//   K1: per-row LN -> normed (f16)  ||  per-block partial sums of |W|
//   K2: reduce partials -> wg; w_bin = clip(round(W/(wg+1e-7)),-1,1) (f16)
//   K3: deep-pipelined dual-GEMM (8-phase-class schedule, counted vmcnt):
//       BM=256 x BNout=128 x BK=64, 8 waves, dbuf 128KB LDS, setprio MFMA.
// ---------------------------------------------------------------------------

#define N_TOK   8192
#define DIMIN   2048
#define DIMOUT  8192
#define NOUT    4096   // DIMOUT/2
#define W_ELEMS 16777216.0f
#define NPART   1024

typedef _Float16 f16x8 __attribute__((ext_vector_type(8)));
typedef _Float16 f16x4 __attribute__((ext_vector_type(4)));
typedef float    f32x4 __attribute__((ext_vector_type(4)));

// ---------------- K1: LN rows -> f16  ||  |W| partial sums ------------------
__global__ __launch_bounds__(256) void ln_wsum_k(
    const float* __restrict__ x, const float* __restrict__ w,
    _Float16* __restrict__ qA, float* __restrict__ wpart) {
    const int b = blockIdx.x;
    const int t = threadIdx.x;
    if (b < N_TOK) {
        __shared__ float sh[8];
        const float4* xr = (const float4*)(x + (size_t)b * DIMIN);
        float4 a = xr[2 * t];
        float4 c = xr[2 * t + 1];
        float s = (a.x + a.y) + (a.z + a.w) + ((c.x + c.y) + (c.z + c.w));
#pragma unroll
        for (int o = 32; o > 0; o >>= 1) s += __shfl_down(s, o, 64);
        if ((t & 63) == 0) sh[t >> 6] = s;
        __syncthreads();
        const float mu = (sh[0] + sh[1] + sh[2] + sh[3]) * (1.0f / DIMIN);

        float d0 = a.x - mu, d1 = a.y - mu, d2 = a.z - mu, d3 = a.w - mu;
        float d4 = c.x - mu, d5 = c.y - mu, d6 = c.z - mu, d7 = c.w - mu;
        float ss = d0*d0 + d1*d1 + d2*d2 + d3*d3 + d4*d4 + d5*d5 + d6*d6 + d7*d7;
#pragma unroll
        for (int o = 32; o > 0; o >>= 1) ss += __shfl_down(ss, o, 64);
        if ((t & 63) == 0) sh[4 + (t >> 6)] = ss;
        __syncthreads();
        const float var = (sh[4] + sh[5] + sh[6] + sh[7]) * (1.0f / DIMIN);
        const float r = rsqrtf(var + 1e-5f);
        f16x8 o;
        o[0] = (_Float16)(d0 * r); o[1] = (_Float16)(d1 * r);
        o[2] = (_Float16)(d2 * r); o[3] = (_Float16)(d3 * r);
        o[4] = (_Float16)(d4 * r); o[5] = (_Float16)(d5 * r);
        o[6] = (_Float16)(d6 * r); o[7] = (_Float16)(d7 * r);
        ((f16x8*)(qA + (size_t)b * DIMIN))[t] = o;
    } else {
        const int p = b - N_TOK;                 // 0..1023
        float acc = 0.0f;
        const float4* w4 = (const float4*)w;
        for (unsigned i = (unsigned)p * 256u + t; i < 4194304u; i += 262144u) {
            float4 v = w4[i];                    // 16 iterations
            acc += (fabsf(v.x) + fabsf(v.y)) + (fabsf(v.z) + fabsf(v.w));
        }
        __shared__ float shw[4];
#pragma unroll
        for (int o = 32; o > 0; o >>= 1) acc += __shfl_down(acc, o, 64);
        if ((t & 63) == 0) shw[t >> 6] = acc;
        __syncthreads();
        if (t == 0) wpart[p] = (shw[0] + shw[1]) + (shw[2] + shw[3]);
    }
}

// ---------------- K2: reduce partials, ternarize W to f16 -------------------
__global__ __launch_bounds__(256) void ternW_k(
    const float* __restrict__ w, const float* __restrict__ wpart,
    float* __restrict__ sc, _Float16* __restrict__ q) {
    const int t = threadIdx.x;
    __shared__ float sh[4];
    float4 p = ((const float4*)wpart)[t];        // 256 threads cover 1024 partials
    float acc = (p.x + p.y) + (p.z + p.w);
#pragma unroll
    for (int o = 32; o > 0; o >>= 1) acc += __shfl_down(acc, o, 64);
    if ((t & 63) == 0) sh[t >> 6] = acc;
    __syncthreads();
    const float wg = ((sh[0] + sh[1]) + (sh[2] + sh[3])) * (1.0f / W_ELEMS);
    if (blockIdx.x == 0 && t == 0) sc[0] = wg;   // for GEMM epilogue
    const float invw = 1.0f / (wg + 1e-7f);
    for (unsigned i = blockIdx.x * 256u + t; i < 4194304u; i += 262144u) {
        float4 v = ((const float4*)w)[i];        // 16 iterations (1024 blocks)
        f16x4 o;
        o.x = (_Float16)fminf(fmaxf(rintf(v.x * invw), -1.0f), 1.0f);
        o.y = (_Float16)fminf(fmaxf(rintf(v.y * invw), -1.0f), 1.0f);
        o.z = (_Float16)fminf(fmaxf(rintf(v.z * invw), -1.0f), 1.0f);
        o.w = (_Float16)fminf(fmaxf(rintf(v.w * invw), -1.0f), 1.0f);
        ((f16x4*)q)[i] = o;
    }
}

// ---------------- K3: deep-pipelined dual GEMM + SiLU gate ------------------
__device__ __forceinline__ void ld16(const _Float16* g, _Float16* l) {
    __builtin_amdgcn_global_load_lds(
        (const __attribute__((address_space(1))) unsigned int*)g,
        (__attribute__((address_space(3))) unsigned int*)l, 16, 0, 0);
}

// LDS map (f16 elems): A buf0 [0,16384) buf1 [16384,32768);
//                      B buf0 [32768,49152) buf1 [49152,65536).
// B rows 0..127 = W rows n0..n0+127 (h); rows 128..255 = n0+4096.. (g).
// Swizzle: logical (row, 16B-granule g) stored at granule g ^ (row&7);
// staging keeps LDS linear and pre-swizzles the GLOBAL source column.
// STAGE issue order: A0 A1 A2 A3 B0 B1 B2 B3  (B2,B3 = g-half, needed one
// phase later than the rest -> counted vmcnt keeps them in flight).
#define STAGE(par) do {                                              \
    _Float16* dA_ = sm + ((par) << 14) + (wave << 9);                \
    _Float16* dB_ = sm + 32768 + ((par) << 14) + (wave << 9);        \
    ld16(pa,            dA_);                                        \
    ld16(pa + 131072,   dA_ + 4096);                                 \
    ld16(pa + 262144,   dA_ + 8192);                                 \
    ld16(pa + 393216,   dA_ + 12288);                                \
    ld16(pb,            dB_);                                        \
    ld16(pb + 131072,   dB_ + 4096);                                 \
    ld16(pb + 8388608,  dB_ + 8192);                                 \
    ld16(pb + 8519680,  dB_ + 12288);                                \
    pa += 64; pb += 64;                                              \
} while (0)

__global__ __launch_bounds__(512, 2) void gemm_glu_k(
    const _Float16* __restrict__ Aq, const _Float16* __restrict__ Wq,
    const float* __restrict__ sc, float* __restrict__ out) {

    __shared__ __align__(16) _Float16 sm[65536];   // 128 KB

    const int tid  = threadIdx.x;
    const int wave = tid >> 6;
    const int lane = tid & 63;

    // bijective XCD swizzle (1024 % 8 == 0): each XCD gets 4 contiguous bm rows
    const int swz = ((blockIdx.x & 7) << 7) + (blockIdx.x >> 3);
    const int m0 = (swz >> 5) << 8;   // tile row * 256
    const int n0 = (swz & 31) << 7;   // tile out-col * 128

    // --- staging addresses (global source pre-swizzled, LDS dest linear) ---
    const int rs = (wave << 3) + (lane >> 3);                  // row in 64-row issue
    const int kc = (((lane & 7) ^ ((lane >> 3) & 7)) << 3);    // swizzled col
    const _Float16* pa = Aq + (size_t)(m0 + rs) * DIMIN + kc;
    const _Float16* pb = Wq + (size_t)(n0 + rs) * DIMIN + kc;

    // --- fragment read offsets (swizzled) ---
    const int fr   = lane & 15;
    const int quad = lane >> 4;
    const int xr   = fr & 7;
    const int wm = (wave >> 1) << 6;   // 0,64,128,192
    const int wn = (wave & 1) << 6;    // 0,64
    const int a0off = (wm + fr) * 64 + ((quad ^ xr) << 3);         // k-slice 0
    const int a1off = (wm + fr) * 64 + (((quad + 4) ^ xr) << 3);   // k-slice 1
    const int b0off = (wn + fr) * 64 + ((quad ^ xr) << 3);
    const int b1off = (wn + fr) * 64 + (((quad + 4) ^ xr) << 3);

    const float s = sc[0];             // w_gamma (uniform scalar load, early)

    f32x4 z = {0.0f, 0.0f, 0.0f, 0.0f};
    f32x4 acc_h[4][4], acc_g[4][4];
#pragma unroll
    for (int i = 0; i < 4; ++i)
#pragma unroll
        for (int j = 0; j < 4; ++j) { acc_h[i][j] = z; acc_g[i][j] = z; }

    // prologue: stage tile 0; wait A+Bh (oldest 6), leave Bg (2) in flight
    STAGE(0);
    asm volatile("s_waitcnt vmcnt(2)" ::: "memory");
    __builtin_amdgcn_s_barrier();

    f16x8 a[4], b[4];
#pragma unroll 2
    for (int t = 0; t < 32; ++t) {
        const _Float16* Ac = sm + ((t & 1) << 14);
        const _Float16* Bc = sm + 32768 + ((t & 1) << 14);
        const bool more = (t < 31);

        // ---- phase 0: (h, k0) + stage next tile ----
#pragma unroll
        for (int i = 0; i < 4; ++i) {
            a[i] = *(const f16x8*)(Ac + a0off + (i << 10));
            b[i] = *(const f16x8*)(Bc + b0off + (i << 10));
        }
        if (more) STAGE((t + 1) & 1);
        __builtin_amdgcn_s_barrier();
        asm volatile("s_waitcnt lgkmcnt(0)" ::: "memory");
        __builtin_amdgcn_s_setprio(1);
#pragma unroll
        for (int mi = 0; mi < 4; ++mi)
#pragma unroll
            for (int ni = 0; ni < 4; ++ni)
                acc_h[mi][ni] = __builtin_amdgcn_mfma_f32_16x16x32_f16(
                    a[mi], b[ni], acc_h[mi][ni], 0, 0, 0);
        __builtin_amdgcn_s_setprio(0);
        if (more) asm volatile("s_waitcnt vmcnt(8)" ::: "memory"); // cur Bg done
        else      asm volatile("s_waitcnt vmcnt(0)" ::: "memory");
        __builtin_amdgcn_s_barrier();

        // ---- phase 1: (g, k0) — reuse a[] ----
#pragma unroll
        for (int i = 0; i < 4; ++i)
            b[i] = *(const f16x8*)(Bc + 8192 + b0off + (i << 10));
        __builtin_amdgcn_s_barrier();
        asm volatile("s_waitcnt lgkmcnt(0)" ::: "memory");
        __builtin_amdgcn_s_setprio(1);
#pragma unroll
        for (int mi = 0; mi < 4; ++mi)
#pragma unroll
            for (int ni = 0; ni < 4; ++ni)
                acc_g[mi][ni] = __builtin_amdgcn_mfma_f32_16x16x32_f16(
                    a[mi], b[ni], acc_g[mi][ni], 0, 0, 0);
        __builtin_amdgcn_s_setprio(0);
        __builtin_amdgcn_s_barrier();

        // ---- phase 2: (h, k1) ----
#pragma unroll
        for (int i = 0; i < 4; ++i) {
            a[i] = *(const f16x8*)(Ac + a1off + (i << 10));
            b[i] = *(const f16x8*)(Bc + b1off + (i << 10));
        }
        __builtin_amdgcn_s_barrier();
        asm volatile("s_waitcnt lgkmcnt(0)" ::: "memory");
        __builtin_amdgcn_s_setprio(1);
#pragma unroll
        for (int mi = 0; mi < 4; ++mi)
#pragma unroll
            for (int ni = 0; ni < 4; ++ni)
                acc_h[mi][ni] = __builtin_amdgcn_mfma_f32_16x16x32_f16(
                    a[mi], b[ni], acc_h[mi][ni], 0, 0, 0);
        __builtin_amdgcn_s_setprio(0);
        __builtin_amdgcn_s_barrier();

        // ---- phase 3: (g, k1) — reuse a[] ----
#pragma unroll
        for (int i = 0; i < 4; ++i)
            b[i] = *(const f16x8*)(Bc + 8192 + b1off + (i << 10));
        __builtin_amdgcn_s_barrier();
        asm volatile("s_waitcnt lgkmcnt(0)" ::: "memory");
        __builtin_amdgcn_s_setprio(1);
#pragma unroll
        for (int mi = 0; mi < 4; ++mi)
#pragma unroll
            for (int ni = 0; ni < 4; ++ni)
                acc_g[mi][ni] = __builtin_amdgcn_mfma_f32_16x16x32_f16(
                    a[mi], b[ni], acc_g[mi][ni], 0, 0, 0);
        __builtin_amdgcn_s_setprio(0);
        if (more) asm volatile("s_waitcnt vmcnt(2)" ::: "memory"); // next A+Bh done
        __builtin_amdgcn_s_barrier();
    }

    // ---- epilogue: GLU combine + store ----
    const int er = quad << 2;          // C/D: col = lane&15, row = quad*4 + r
#pragma unroll
    for (int mi = 0; mi < 4; ++mi)
#pragma unroll
        for (int ni = 0; ni < 4; ++ni)
#pragma unroll
            for (int r = 0; r < 4; ++r) {
                const int m = m0 + wm + (mi << 4) + er + r;
                const int n = n0 + wn + (ni << 4) + fr;
                const float h = acc_h[mi][ni][r] * s;
                const float g = acc_g[mi][ni][r] * s;
                out[(size_t)m * NOUT + n] = h * g / (1.0f + __expf(-g));
            }
}

// ---------------------------------------------------------------------------
extern "C" void kernel_launch(void* const* d_in, const int* in_sizes, int n_in,
                              void* d_out, int out_size, void* d_ws, size_t ws_size,
                              hipStream_t stream) {
    const float* x = (const float*)d_in[0];
    const float* w = (const float*)d_in[1];
    float* out = (float*)d_out;   // reference output dtype is float32

    char* ws = (char*)d_ws;
    float* sc    = (float*)ws;                                // [0] = wg
    float* wpart = (float*)(ws + 4096);                       // 1024 partials
    _Float16* qA = (_Float16*)(ws + 16384);                   // 32 MB normed f16
    _Float16* wB = (_Float16*)(ws + 16384 + 33554432);        // 32 MB ternary f16

    ln_wsum_k<<<N_TOK + NPART, 256, 0, stream>>>(x, w, qA, wpart);
    ternW_k<<<NPART, 256, 0, stream>>>(w, wpart, sc, wB);

    gemm_glu_k<<<dim3(1024), dim3(512), 0, stream>>>(qA, wB, sc, out);
}

// Round 4
// 450.451 us; speedup vs baseline: 1.0719x; 1.0462x over previous
//
#include <hip/hip_runtime.h>
#include <hip/hip_bf16.h>
#include <cstdint>

// ---------------------------------------------------------------------------
// BitLinear GLU: x[8192,2048] f32, W[8192,2048] f32 -> out[8192,4096] f32
//   Identity: out = (normed @ w_bin^T) * w_gamma  -- input_gamma cancels
//   K1: per-row LN -> normed (f16)  ||  per-block partial sums of |W|
//   K2: reduce partials -> wg; w_bin = clip(round(W/(wg+1e-7)),-1,1) (f16)
//   K3: dual-GEMM, m201-style schedule: 4 phases/K-tile, 2 global_load_lds
//       issued per phase (fine interleave, m196), counted vmcnt(2) 2x/tile
//       (never 0 in steady state), setprio(1) around each 16-MFMA cluster.
// ---------------------------------------------------------------------------

#define N_TOK   8192
#define DIMIN   2048
#define DIMOUT  8192
#define NOUT    4096   // DIMOUT/2
#define W_ELEMS 16777216.0f
#define NPART   1024

typedef _Float16 f16x8 __attribute__((ext_vector_type(8)));
typedef _Float16 f16x4 __attribute__((ext_vector_type(4)));
typedef float    f32x4 __attribute__((ext_vector_type(4)));

// ---------------- K1: LN rows -> f16  ||  |W| partial sums ------------------
__global__ __launch_bounds__(256) void ln_wsum_k(
    const float* __restrict__ x, const float* __restrict__ w,
    _Float16* __restrict__ qA, float* __restrict__ wpart) {
    const int b = blockIdx.x;
    const int t = threadIdx.x;
    if (b < N_TOK) {
        __shared__ float sh[8];
        const float4* xr = (const float4*)(x + (size_t)b * DIMIN);
        float4 a = xr[2 * t];
        float4 c = xr[2 * t + 1];
        float s = (a.x + a.y) + (a.z + a.w) + ((c.x + c.y) + (c.z + c.w));
#pragma unroll
        for (int o = 32; o > 0; o >>= 1) s += __shfl_down(s, o, 64);
        if ((t & 63) == 0) sh[t >> 6] = s;
        __syncthreads();
        const float mu = (sh[0] + sh[1] + sh[2] + sh[3]) * (1.0f / DIMIN);

        float d0 = a.x - mu, d1 = a.y - mu, d2 = a.z - mu, d3 = a.w - mu;
        float d4 = c.x - mu, d5 = c.y - mu, d6 = c.z - mu, d7 = c.w - mu;
        float ss = d0*d0 + d1*d1 + d2*d2 + d3*d3 + d4*d4 + d5*d5 + d6*d6 + d7*d7;
#pragma unroll
        for (int o = 32; o > 0; o >>= 1) ss += __shfl_down(ss, o, 64);
        if ((t & 63) == 0) sh[4 + (t >> 6)] = ss;
        __syncthreads();
        const float var = (sh[4] + sh[5] + sh[6] + sh[7]) * (1.0f / DIMIN);
        const float r = rsqrtf(var + 1e-5f);
        f16x8 o;
        o[0] = (_Float16)(d0 * r); o[1] = (_Float16)(d1 * r);
        o[2] = (_Float16)(d2 * r); o[3] = (_Float16)(d3 * r);
        o[4] = (_Float16)(d4 * r); o[5] = (_Float16)(d5 * r);
        o[6] = (_Float16)(d6 * r); o[7] = (_Float16)(d7 * r);
        ((f16x8*)(qA + (size_t)b * DIMIN))[t] = o;
    } else {
        const int p = b - N_TOK;                 // 0..1023
        float acc = 0.0f;
        const float4* w4 = (const float4*)w;
        for (unsigned i = (unsigned)p * 256u + t; i < 4194304u; i += 262144u) {
            float4 v = w4[i];                    // 16 iterations
            acc += (fabsf(v.x) + fabsf(v.y)) + (fabsf(v.z) + fabsf(v.w));
        }
        __shared__ float shw[4];
#pragma unroll
        for (int o = 32; o > 0; o >>= 1) acc += __shfl_down(acc, o, 64);
        if ((t & 63) == 0) shw[t >> 6] = acc;
        __syncthreads();
        if (t == 0) wpart[p] = (shw[0] + shw[1]) + (shw[2] + shw[3]);
    }
}

// ---------------- K2: reduce partials, ternarize W to f16 -------------------
__global__ __launch_bounds__(256) void ternW_k(
    const float* __restrict__ w, const float* __restrict__ wpart,
    float* __restrict__ sc, _Float16* __restrict__ q) {
    const int t = threadIdx.x;
    __shared__ float sh[4];
    float4 p = ((const float4*)wpart)[t];        // 256 threads cover 1024 partials
    float acc = (p.x + p.y) + (p.z + p.w);
#pragma unroll
    for (int o = 32; o > 0; o >>= 1) acc += __shfl_down(acc, o, 64);
    if ((t & 63) == 0) sh[t >> 6] = acc;
    __syncthreads();
    const float wg = ((sh[0] + sh[1]) + (sh[2] + sh[3])) * (1.0f / W_ELEMS);
    if (blockIdx.x == 0 && t == 0) sc[0] = wg;   // for GEMM epilogue
    const float invw = 1.0f / (wg + 1e-7f);
    for (unsigned i = blockIdx.x * 256u + t; i < 4194304u; i += 262144u) {
        float4 v = ((const float4*)w)[i];        // 16 iterations (1024 blocks)
        f16x4 o;
        o.x = (_Float16)fminf(fmaxf(rintf(v.x * invw), -1.0f), 1.0f);
        o.y = (_Float16)fminf(fmaxf(rintf(v.y * invw), -1.0f), 1.0f);
        o.z = (_Float16)fminf(fmaxf(rintf(v.z * invw), -1.0f), 1.0f);
        o.w = (_Float16)fminf(fmaxf(rintf(v.w * invw), -1.0f), 1.0f);
        ((f16x4*)q)[i] = o;
    }
}

// ---------------- K3: deep-pipelined dual GEMM + SiLU gate ------------------
__device__ __forceinline__ void ld16(const _Float16* g, _Float16* l) {
    __builtin_amdgcn_global_load_lds(
        (const __attribute__((address_space(1))) unsigned int*)g,
        (__attribute__((address_space(3))) unsigned int*)l, 16, 0, 0);
}

// LDS map (f16 elems): A buf0 [0,16384) buf1 [16384,32768);
//                      B buf0 [32768,49152) buf1 [49152,65536).
// B rows 0..127 = W rows n0..n0+127 (h); rows 128..255 = n0+4096.. (g).
// Swizzle: logical (row, 16B-granule g) stored at granule g ^ (row&7);
// staging keeps LDS linear and pre-swizzles the GLOBAL source column.
//
// Schedule (m201): 4 phases/K-tile, each {ds_read frags; issue 2
// global_load_lds of NEXT tile; barrier; lgkmcnt(0); setprio(1); 16 MFMA;
// setprio(0); [vmcnt(2)]; barrier}. Issue order Bh0,Bh1 | A0,A1 | A2,A3 |
// Bg0,Bg1 -- Bg last so vmcnt(2) can leave it in flight (it is consumed one
// phase later than the rest). W-halves get the longest latency gaps (W
// streams 32MB/XCD -> L2-miss-prone; A's 4MB panel is L2-resident).

#define BAR    __builtin_amdgcn_s_barrier()
#define LGKM0  asm volatile("s_waitcnt lgkmcnt(0)" ::: "memory")
#define VMC(n) asm volatile("s_waitcnt vmcnt(" #n ")" ::: "memory")
#define PRIO1  __builtin_amdgcn_s_setprio(1)
#define PRIO0  __builtin_amdgcn_s_setprio(0)

#define MFMA16(ACC)                                                       \
    _Pragma("unroll") for (int mi = 0; mi < 4; ++mi)                      \
    _Pragma("unroll") for (int ni = 0; ni < 4; ++ni)                      \
        ACC[mi][ni] = __builtin_amdgcn_mfma_f32_16x16x32_f16(             \
            a[mi], b[ni], ACC[mi][ni], 0, 0, 0);

#define DS_AB(AOFF, BOFF_)                                                \
    _Pragma("unroll") for (int i = 0; i < 4; ++i) {                       \
        a[i] = *(const f16x8*)(Ac + (AOFF) + (i << 10));                  \
        b[i] = *(const f16x8*)(Bc + (BOFF_) + (i << 10));                 \
    }

#define DS_B(BOFF_)                                                       \
    _Pragma("unroll") for (int i = 0; i < 4; ++i)                         \
        b[i] = *(const f16x8*)(Bc + (BOFF_) + (i << 10));

__global__ __launch_bounds__(512, 2) void gemm_glu_k(
    const _Float16* __restrict__ Aq, const _Float16* __restrict__ Wq,
    const float* __restrict__ sc, float* __restrict__ out) {

    __shared__ __align__(16) _Float16 sm[65536];   // 128 KB

    const int tid  = threadIdx.x;
    const int wave = tid >> 6;
    const int lane = tid & 63;

    // bijective XCD swizzle (1024 % 8 == 0): each XCD gets 4 contiguous bm rows
    const int swz = ((blockIdx.x & 7) << 7) + (blockIdx.x >> 3);
    const int m0 = (swz >> 5) << 8;   // tile row * 256
    const int n0 = (swz & 31) << 7;   // tile out-col * 128

    // --- staging addresses (global source pre-swizzled, LDS dest linear) ---
    const int rs = (wave << 3) + (lane >> 3);                  // row in 64-row stripe
    const int kc = (((lane & 7) ^ ((lane >> 3) & 7)) << 3);    // swizzled col
    const _Float16* pa = Aq + (size_t)(m0 + rs) * DIMIN + kc;
    const _Float16* pb = Wq + (size_t)(n0 + rs) * DIMIN + kc;

    // --- fragment read offsets (swizzled) ---
    const int fr   = lane & 15;
    const int quad = lane >> 4;
    const int xr   = fr & 7;
    const int wm = (wave >> 1) << 6;   // 0,64,128,192
    const int wn = (wave & 1) << 6;    // 0,64
    const int a0off = (wm + fr) * 64 + ((quad ^ xr) << 3);         // k-slice 0
    const int a1off = (wm + fr) * 64 + (((quad + 4) ^ xr) << 3);   // k-slice 1
    const int b0off = (wn + fr) * 64 + ((quad ^ xr) << 3);
    const int b1off = (wn + fr) * 64 + (((quad + 4) ^ xr) << 3);

    const float s = sc[0];             // w_gamma (uniform scalar load, early)

    f32x4 z = {0.0f, 0.0f, 0.0f, 0.0f};
    f32x4 acc_h[4][4], acc_g[4][4];
#pragma unroll
    for (int i = 0; i < 4; ++i)
#pragma unroll
        for (int j = 0; j < 4; ++j) { acc_h[i][j] = z; acc_g[i][j] = z; }

    // ---- prologue: stage tile 0 into buf0 (Bg issued last) ----
    {
        _Float16* dA = sm + (wave << 9);
        _Float16* dB = dA + 32768;
        ld16(pb,           dB);            // Bh0
        ld16(pb + 131072,  dB + 4096);     // Bh1
        ld16(pa,           dA);            // A0
        ld16(pa + 131072,  dA + 4096);     // A1
        ld16(pa + 262144,  dA + 8192);     // A2
        ld16(pa + 393216,  dA + 12288);    // A3
        ld16(pb + 8388608, dB + 8192);     // Bg0
        ld16(pb + 8519680, dB + 12288);    // Bg1
        pa += 64; pb += 64;
    }
    VMC(2);            // A+Bh of tile 0 landed; Bg still in flight
    BAR;

    f16x8 a[4], b[4];
    for (int t = 0; t < 31; ++t) {         // steady state: stages tile t+1
        const _Float16* Ac = sm + ((t & 1) << 14);
        const _Float16* Bc = Ac + 32768;
        _Float16* dA = sm + (((t + 1) & 1) << 14) + (wave << 9);
        _Float16* dB = dA + 32768;

        // ---- phase 0: (h, k0) ----
        DS_AB(a0off, b0off);
        ld16(pb,          dB);             // Bh0 (t+1)
        ld16(pb + 131072, dB + 4096);      // Bh1 (t+1)
        BAR; LGKM0;
        PRIO1; MFMA16(acc_h); PRIO0;
        VMC(2);                            // retire Bg of tile t
        BAR;

        // ---- phase 1: (g, k0) -- reuse a[] ----
        DS_B(8192 + b0off);
        ld16(pa,          dA);             // A0 (t+1)
        ld16(pa + 131072, dA + 4096);      // A1 (t+1)
        BAR; LGKM0;
        PRIO1; MFMA16(acc_g); PRIO0;
        BAR;

        // ---- phase 2: (h, k1) ----
        DS_AB(a1off, b1off);
        ld16(pa + 262144, dA + 8192);      // A2 (t+1)
        ld16(pa + 393216, dA + 12288);     // A3 (t+1)
        BAR; LGKM0;
        PRIO1; MFMA16(acc_h); PRIO0;
        BAR;

        // ---- phase 3: (g, k1) -- reuse a[] ----
        DS_B(8192 + b1off);
        ld16(pb + 8388608, dB + 8192);     // Bg0 (t+1)
        ld16(pb + 8519680, dB + 12288);    // Bg1 (t+1)
        BAR; LGKM0;
        PRIO1; MFMA16(acc_g); PRIO0;
        VMC(2);                            // retire A+Bh of tile t+1; keep Bg
        BAR;

        pa += 64; pb += 64;
    }

    // ---- tail tile (t = 31, buf 1, no staging) ----
    {
        const _Float16* Ac = sm + 16384;
        const _Float16* Bc = Ac + 32768;

        DS_AB(a0off, b0off);
        BAR; LGKM0;
        PRIO1; MFMA16(acc_h); PRIO0;
        VMC(0);                            // drain Bg of tile 31
        BAR;

        DS_B(8192 + b0off);
        BAR; LGKM0;
        PRIO1; MFMA16(acc_g); PRIO0;
        BAR;

        DS_AB(a1off, b1off);
        BAR; LGKM0;
        PRIO1; MFMA16(acc_h); PRIO0;
        BAR;

        DS_B(8192 + b1off);
        BAR; LGKM0;
        PRIO1; MFMA16(acc_g); PRIO0;
    }

    // ---- epilogue: GLU combine + store ----
    const int er = quad << 2;          // C/D: col = lane&15, row = quad*4 + r
#pragma unroll
    for (int mi = 0; mi < 4; ++mi)
#pragma unroll
        for (int ni = 0; ni < 4; ++ni)
#pragma unroll
            for (int r = 0; r < 4; ++r) {
                const int m = m0 + wm + (mi << 4) + er + r;
                const int n = n0 + wn + (ni << 4) + fr;
                const float h = acc_h[mi][ni][r] * s;
                const float g = acc_g[mi][ni][r] * s;
                out[(size_t)m * NOUT + n] = h * g / (1.0f + __expf(-g));
            }
}

// ---------------------------------------------------------------------------
extern "C" void kernel_launch(void* const* d_in, const int* in_sizes, int n_in,
                              void* d_out, int out_size, void* d_ws, size_t ws_size,
                              hipStream_t stream) {
    const float* x = (const float*)d_in[0];
    const float* w = (const float*)d_in[1];
    float* out = (float*)d_out;   // reference output dtype is float32

    char* ws = (char*)d_ws;
    float* sc    = (float*)ws;                                // [0] = wg
    float* wpart = (float*)(ws + 4096);                       // 1024 partials
    _Float16* qA = (_Float16*)(ws + 16384);                   // 32 MB normed f16
    _Float16* wB = (_Float16*)(ws + 16384 + 33554432);        // 32 MB ternary f16

    ln_wsum_k<<<N_TOK + NPART, 256, 0, stream>>>(x, w, qA, wpart);
    ternW_k<<<NPART, 256, 0, stream>>>(w, wpart, sc, wB);

    gemm_glu_k<<<dim3(1024), dim3(512), 0, stream>>>(qA, wB, sc, out);
}

// Round 5
// 447.720 us; speedup vs baseline: 1.0785x; 1.0061x over previous
//
#include <hip/hip_runtime.h>
#include <hip/hip_bf16.h>
#include <cstdint>

// ---------------------------------------------------------------------------
// BitLinear GLU: x[8192,2048] f32, W[8192,2048] f32 -> out[8192,4096] f32
//   Identity: out = (normed @ w_bin^T) * w_gamma  -- input_gamma cancels
//   K1: per-row LN (1 wave/row, shfl-only) -> f16  ||  |W| partial sums
//   K2: reduce partials -> wg; w_bin = clip(round(W/(wg+1e-7)),-1,1) (f16)
//   K3: dual-GEMM, 4 phases/K-tile ordered (h,k0)(h,k1)(g,k0)(g,k1) so the
//       L2-missing W loads get >=2 phases of latency cover; counted vmcnt
//       (4 then 2, never 0 in steady state); setprio around MFMA clusters.
// ---------------------------------------------------------------------------

#define N_TOK   8192
#define DIMIN   2048
#define DIMOUT  8192
#define NOUT    4096   // DIMOUT/2
#define W_ELEMS 16777216.0f
#define NPART   1024
#define NLNB    2048   // LN blocks: 4 rows per block, 1 wave per row

typedef _Float16 f16x8 __attribute__((ext_vector_type(8)));
typedef _Float16 f16x4 __attribute__((ext_vector_type(4)));
typedef float    f32x4 __attribute__((ext_vector_type(4)));

// ---------------- K1: LN rows (wave-per-row) || |W| partial sums ------------
__global__ __launch_bounds__(256) void ln_wsum_k(
    const float* __restrict__ x, const float* __restrict__ w,
    _Float16* __restrict__ qA, float* __restrict__ wpart) {
    const int b = blockIdx.x;
    const int t = threadIdx.x;
    if (b < NLNB) {
        // 4 rows per block, one wave each: no LDS, no __syncthreads.
        const int wv  = t >> 6;
        const int ln  = t & 63;
        const int row = (b << 2) + wv;
        const float4* xr = (const float4*)(x + (size_t)row * DIMIN);
        float4 v[8];
#pragma unroll
        for (int j = 0; j < 4; ++j) {
            v[2 * j]     = xr[2 * ln + 128 * j];
            v[2 * j + 1] = xr[2 * ln + 128 * j + 1];
        }
        float s = 0.0f;
#pragma unroll
        for (int j = 0; j < 8; ++j) s += (v[j].x + v[j].y) + (v[j].z + v[j].w);
#pragma unroll
        for (int o = 32; o > 0; o >>= 1) s += __shfl_xor(s, o, 64);
        const float mu = s * (1.0f / DIMIN);

        float ss = 0.0f;
#pragma unroll
        for (int j = 0; j < 8; ++j) {
            float d0 = v[j].x - mu, d1 = v[j].y - mu;
            float d2 = v[j].z - mu, d3 = v[j].w - mu;
            ss += (d0 * d0 + d1 * d1) + (d2 * d2 + d3 * d3);
        }
#pragma unroll
        for (int o = 32; o > 0; o >>= 1) ss += __shfl_xor(ss, o, 64);
        const float var = ss * (1.0f / DIMIN);
        const float r = rsqrtf(var + 1e-5f);

        f16x8* qr = (f16x8*)(qA + (size_t)row * DIMIN);
#pragma unroll
        for (int j = 0; j < 4; ++j) {
            const float4 u0 = v[2 * j], u1 = v[2 * j + 1];
            f16x8 o;
            o[0] = (_Float16)((u0.x - mu) * r); o[1] = (_Float16)((u0.y - mu) * r);
            o[2] = (_Float16)((u0.z - mu) * r); o[3] = (_Float16)((u0.w - mu) * r);
            o[4] = (_Float16)((u1.x - mu) * r); o[5] = (_Float16)((u1.y - mu) * r);
            o[6] = (_Float16)((u1.z - mu) * r); o[7] = (_Float16)((u1.w - mu) * r);
            qr[ln + 64 * j] = o;
        }
    } else {
        const int p = b - NLNB;                  // 0..1023
        float acc = 0.0f;
        const float4* w4 = (const float4*)w;
        for (unsigned i = (unsigned)p * 256u + t; i < 4194304u; i += 262144u) {
            float4 v = w4[i];                    // 16 iterations
            acc += (fabsf(v.x) + fabsf(v.y)) + (fabsf(v.z) + fabsf(v.w));
        }
        __shared__ float shw[4];
#pragma unroll
        for (int o = 32; o > 0; o >>= 1) acc += __shfl_down(acc, o, 64);
        if ((t & 63) == 0) shw[t >> 6] = acc;
        __syncthreads();
        if (t == 0) wpart[p] = (shw[0] + shw[1]) + (shw[2] + shw[3]);
    }
}

// ---------------- K2: reduce partials, ternarize W to f16 -------------------
__global__ __launch_bounds__(256) void ternW_k(
    const float* __restrict__ w, const float* __restrict__ wpart,
    float* __restrict__ sc, _Float16* __restrict__ q) {
    const int t = threadIdx.x;
    __shared__ float sh[4];
    float4 p = ((const float4*)wpart)[t];        // 256 threads cover 1024 partials
    float acc = (p.x + p.y) + (p.z + p.w);
#pragma unroll
    for (int o = 32; o > 0; o >>= 1) acc += __shfl_down(acc, o, 64);
    if ((t & 63) == 0) sh[t >> 6] = acc;
    __syncthreads();
    const float wg = ((sh[0] + sh[1]) + (sh[2] + sh[3])) * (1.0f / W_ELEMS);
    if (blockIdx.x == 0 && t == 0) sc[0] = wg;   // for GEMM epilogue
    const float invw = 1.0f / (wg + 1e-7f);
    for (unsigned i = blockIdx.x * 256u + t; i < 4194304u; i += 262144u) {
        float4 v = ((const float4*)w)[i];        // 16 iterations (1024 blocks)
        f16x4 o;
        o.x = (_Float16)fminf(fmaxf(rintf(v.x * invw), -1.0f), 1.0f);
        o.y = (_Float16)fminf(fmaxf(rintf(v.y * invw), -1.0f), 1.0f);
        o.z = (_Float16)fminf(fmaxf(rintf(v.z * invw), -1.0f), 1.0f);
        o.w = (_Float16)fminf(fmaxf(rintf(v.w * invw), -1.0f), 1.0f);
        ((f16x4*)q)[i] = o;
    }
}

// ---------------- K3: deep-pipelined dual GEMM + SiLU gate ------------------
__device__ __forceinline__ void ld16(const _Float16* g, _Float16* l) {
    __builtin_amdgcn_global_load_lds(
        (const __attribute__((address_space(1))) unsigned int*)g,
        (__attribute__((address_space(3))) unsigned int*)l, 16, 0, 0);
}

// LDS map (f16 elems): A buf0 [0,16384) buf1 [16384,32768);
//                      B buf0 [32768,49152) buf1 [49152,65536).
// B rows 0..127 = W rows n0..n0+127 (h); rows 128..255 = n0+4096.. (g).
// Swizzle: logical (row, 16B-granule g) stored at granule g ^ (row&7);
// staging keeps LDS linear and pre-swizzles the GLOBAL source column.
//
// Phase order (h,k0)(h,k1)(g,k0)(g,k1): Bg(t) is first read at P2, so its
// wait (end-P1, vmcnt(4)) sits 2 full phases after its issue (P3 of t-1) --
// covers L3 latency (W misses the per-XCD L2). Issue: Bh@P0 (3-phase cover),
// A@P1/P2 (L2-resident, 1-2 phases suffice), Bg@P3. vmcnt never 0 in loop.

#define BAR    __builtin_amdgcn_s_barrier()
#define LGKM0  asm volatile("s_waitcnt lgkmcnt(0)" ::: "memory")
#define VMC(n) asm volatile("s_waitcnt vmcnt(" #n ")" ::: "memory")
#define PRIO1  __builtin_amdgcn_s_setprio(1)
#define PRIO0  __builtin_amdgcn_s_setprio(0)

#define MFMA16(AARR, ACC)                                                 \
    _Pragma("unroll") for (int mi = 0; mi < 4; ++mi)                      \
    _Pragma("unroll") for (int ni = 0; ni < 4; ++ni)                      \
        ACC[mi][ni] = __builtin_amdgcn_mfma_f32_16x16x32_f16(             \
            AARR[mi], b[ni], ACC[mi][ni], 0, 0, 0);

#define DSA(AARR, AOFF)                                                   \
    _Pragma("unroll") for (int i = 0; i < 4; ++i)                         \
        AARR[i] = *(const f16x8*)(Ac + (AOFF) + (i << 10));

#define DSB(BOFF_)                                                        \
    _Pragma("unroll") for (int i = 0; i < 4; ++i)                         \
        b[i] = *(const f16x8*)(Bc + (BOFF_) + (i << 10));

__global__ __launch_bounds__(512, 2) void gemm_glu_k(
    const _Float16* __restrict__ Aq, const _Float16* __restrict__ Wq,
    const float* __restrict__ sc, float* __restrict__ out) {

    __shared__ __align__(16) _Float16 sm[65536];   // 128 KB

    const int tid  = threadIdx.x;
    const int wave = tid >> 6;
    const int lane = tid & 63;

    // bijective XCD swizzle (1024 % 8 == 0)
    const int swz = ((blockIdx.x & 7) << 7) + (blockIdx.x >> 3);
    const int m0 = (swz >> 5) << 8;   // tile row * 256
    const int n0 = (swz & 31) << 7;   // tile out-col * 128

    // --- staging addresses (global source pre-swizzled, LDS dest linear) ---
    const int rs = (wave << 3) + (lane >> 3);                  // row in 64-row stripe
    const int kc = (((lane & 7) ^ ((lane >> 3) & 7)) << 3);    // swizzled col
    const _Float16* pa = Aq + (size_t)(m0 + rs) * DIMIN + kc;
    const _Float16* pb = Wq + (size_t)(n0 + rs) * DIMIN + kc;

    // --- fragment read offsets (swizzled) ---
    const int fr   = lane & 15;
    const int quad = lane >> 4;
    const int xr   = fr & 7;
    const int wm = (wave >> 1) << 6;   // 0,64,128,192
    const int wn = (wave & 1) << 6;    // 0,64
    const int a0off = (wm + fr) * 64 + ((quad ^ xr) << 3);         // k-slice 0
    const int a1off = (wm + fr) * 64 + (((quad + 4) ^ xr) << 3);   // k-slice 1
    const int b0off = (wn + fr) * 64 + ((quad ^ xr) << 3);
    const int b1off = (wn + fr) * 64 + (((quad + 4) ^ xr) << 3);

    const float s = sc[0];             // w_gamma (uniform scalar load, early)

    f32x4 z = {0.0f, 0.0f, 0.0f, 0.0f};
    f32x4 acc_h[4][4], acc_g[4][4];
#pragma unroll
    for (int i = 0; i < 4; ++i)
#pragma unroll
        for (int j = 0; j < 4; ++j) { acc_h[i][j] = z; acc_g[i][j] = z; }

    // ---- prologue: stage tile 0 into buf0 (order Bh, A, Bg) ----
    {
        _Float16* dA = sm + (wave << 9);
        _Float16* dB = dA + 32768;
        ld16(pb,           dB);            // Bh0
        ld16(pb + 131072,  dB + 4096);     // Bh1
        ld16(pa,           dA);            // A0
        ld16(pa + 131072,  dA + 4096);     // A1
        ld16(pa + 262144,  dA + 8192);     // A2
        ld16(pa + 393216,  dA + 12288);    // A3
        ld16(pb + 8388608, dB + 8192);     // Bg0
        ld16(pb + 8519680, dB + 12288);    // Bg1
        pa += 64; pb += 64;
    }
    VMC(2);            // Bh+A of tile 0 landed; Bg(0) still in flight
    BAR;

    f16x8 a0[4], a1[4], b[4];
    for (int t = 0; t < 31; ++t) {         // steady state: stages tile t+1
        const _Float16* Ac = sm + ((t & 1) << 14);
        const _Float16* Bc = Ac + 32768;
        _Float16* dA = sm + (((t + 1) & 1) << 14) + (wave << 9);
        _Float16* dB = dA + 32768;

        // ---- P0: (h, k0) ----
        DSA(a0, a0off); DSB(b0off);
        ld16(pb,          dB);             // Bh0 (t+1)
        ld16(pb + 131072, dB + 4096);      // Bh1 (t+1)
        BAR; LGKM0;
        PRIO1; MFMA16(a0, acc_h); PRIO0;
        BAR;

        // ---- P1: (h, k1) ----
        DSA(a1, a1off); DSB(b1off);
        ld16(pa,          dA);             // A0 (t+1)
        ld16(pa + 131072, dA + 4096);      // A1 (t+1)
        BAR; LGKM0;
        PRIO1; MFMA16(a1, acc_h); PRIO0;
        VMC(4);                            // retire Bg(t) before P2 reads it
        BAR;

        // ---- P2: (g, k0) -- reuse a0 ----
        DSB(8192 + b0off);
        ld16(pa + 262144, dA + 8192);      // A2 (t+1)
        ld16(pa + 393216, dA + 12288);     // A3 (t+1)
        BAR; LGKM0;
        PRIO1; MFMA16(a0, acc_g); PRIO0;
        BAR;

        // ---- P3: (g, k1) -- reuse a1 ----
        DSB(8192 + b1off);
        ld16(pb + 8388608, dB + 8192);     // Bg0 (t+1)
        ld16(pb + 8519680, dB + 12288);    // Bg1 (t+1)
        BAR; LGKM0;
        PRIO1; MFMA16(a1, acc_g); PRIO0;
        VMC(2);                            // retire Bh+A (t+1); keep Bg (t+1)
        BAR;

        pa += 64; pb += 64;
    }

    // ---- tail tile (t = 31, buf 1, no staging) ----
    {
        const _Float16* Ac = sm + 16384;
        const _Float16* Bc = Ac + 32768;

        DSA(a0, a0off); DSB(b0off);
        BAR; LGKM0;
        PRIO1; MFMA16(a0, acc_h); PRIO0;
        BAR;

        DSA(a1, a1off); DSB(b1off);
        BAR; LGKM0;
        PRIO1; MFMA16(a1, acc_h); PRIO0;
        VMC(0);                            // drain Bg(31)
        BAR;

        DSB(8192 + b0off);
        BAR; LGKM0;
        PRIO1; MFMA16(a0, acc_g); PRIO0;
        BAR;

        DSB(8192 + b1off);
        BAR; LGKM0;
        PRIO1; MFMA16(a1, acc_g); PRIO0;
    }

    // ---- epilogue: GLU combine + store ----
    const int er = quad << 2;          // C/D: col = lane&15, row = quad*4 + r
#pragma unroll
    for (int mi = 0; mi < 4; ++mi)
#pragma unroll
        for (int ni = 0; ni < 4; ++ni)
#pragma unroll
            for (int r = 0; r < 4; ++r) {
                const int m = m0 + wm + (mi << 4) + er + r;
                const int n = n0 + wn + (ni << 4) + fr;
                const float h = acc_h[mi][ni][r] * s;
                const float g = acc_g[mi][ni][r] * s;
                out[(size_t)m * NOUT + n] = h * g / (1.0f + __expf(-g));
            }
}

// ---------------------------------------------------------------------------
extern "C" void kernel_launch(void* const* d_in, const int* in_sizes, int n_in,
                              void* d_out, int out_size, void* d_ws, size_t ws_size,
                              hipStream_t stream) {
    const float* x = (const float*)d_in[0];
    const float* w = (const float*)d_in[1];
    float* out = (float*)d_out;   // reference output dtype is float32

    char* ws = (char*)d_ws;
    float* sc    = (float*)ws;                                // [0] = wg
    float* wpart = (float*)(ws + 4096);                       // 1024 partials
    _Float16* qA = (_Float16*)(ws + 16384);                   // 32 MB normed f16
    _Float16* wB = (_Float16*)(ws + 16384 + 33554432);        // 32 MB ternary f16

    ln_wsum_k<<<NLNB + NPART, 256, 0, stream>>>(x, w, qA, wpart);
    ternW_k<<<NPART, 256, 0, stream>>>(w, wpart, sc, wB);

    gemm_glu_k<<<dim3(1024), dim3(512), 0, stream>>>(qA, wB, sc, out);
}

// Round 6
// 443.299 us; speedup vs baseline: 1.0892x; 1.0100x over previous
//
#include <hip/hip_runtime.h>
#include <hip/hip_bf16.h>
#include <cstdint>

// ---------------------------------------------------------------------------
// BitLinear GLU: x[8192,2048] f32, W[8192,2048] f32 -> out[8192,4096] f32
//   Identity: out = (normed @ w_bin^T) * w_gamma  -- input_gamma cancels
//   K1: per-row LN (1 wave/row, shfl-only) -> f16  ||  |W| partial sums
//   K2: reduce partials -> wg; w_bin = clip(round(W/(wg+1e-7)),-1,1) (f16)
//   K3: dual-GEMM, free-running 4-phase K-tiles with the MINIMUM barrier set:
//       2 barriers/K-tile (Bg-staged, tile-done) + counted vmcnt; waves skew
//       freely between barriers so MFMA of one wave overlaps ds_read/issue of
//       another (m114). Compiler emits fine-grained lgkmcnt for ds->MFMA.
// ---------------------------------------------------------------------------

#define N_TOK   8192
#define DIMIN   2048
#define DIMOUT  8192
#define NOUT    4096   // DIMOUT/2
#define W_ELEMS 16777216.0f
#define NPART   1024
#define NLNB    2048   // LN blocks: 4 rows per block, 1 wave per row

typedef _Float16 f16x8 __attribute__((ext_vector_type(8)));
typedef _Float16 f16x4 __attribute__((ext_vector_type(4)));
typedef float    f32x4 __attribute__((ext_vector_type(4)));

// ---------------- K1: LN rows (wave-per-row) || |W| partial sums ------------
__global__ __launch_bounds__(256) void ln_wsum_k(
    const float* __restrict__ x, const float* __restrict__ w,
    _Float16* __restrict__ qA, float* __restrict__ wpart) {
    const int b = blockIdx.x;
    const int t = threadIdx.x;
    if (b < NLNB) {
        // 4 rows per block, one wave each: no LDS, no __syncthreads.
        const int wv  = t >> 6;
        const int ln  = t & 63;
        const int row = (b << 2) + wv;
        const float4* xr = (const float4*)(x + (size_t)row * DIMIN);
        float4 v[8];
#pragma unroll
        for (int j = 0; j < 4; ++j) {
            v[2 * j]     = xr[2 * ln + 128 * j];
            v[2 * j + 1] = xr[2 * ln + 128 * j + 1];
        }
        float s = 0.0f;
#pragma unroll
        for (int j = 0; j < 8; ++j) s += (v[j].x + v[j].y) + (v[j].z + v[j].w);
#pragma unroll
        for (int o = 32; o > 0; o >>= 1) s += __shfl_xor(s, o, 64);
        const float mu = s * (1.0f / DIMIN);

        float ss = 0.0f;
#pragma unroll
        for (int j = 0; j < 8; ++j) {
            float d0 = v[j].x - mu, d1 = v[j].y - mu;
            float d2 = v[j].z - mu, d3 = v[j].w - mu;
            ss += (d0 * d0 + d1 * d1) + (d2 * d2 + d3 * d3);
        }
#pragma unroll
        for (int o = 32; o > 0; o >>= 1) ss += __shfl_xor(ss, o, 64);
        const float var = ss * (1.0f / DIMIN);
        const float r = rsqrtf(var + 1e-5f);

        f16x8* qr = (f16x8*)(qA + (size_t)row * DIMIN);
#pragma unroll
        for (int j = 0; j < 4; ++j) {
            const float4 u0 = v[2 * j], u1 = v[2 * j + 1];
            f16x8 o;
            o[0] = (_Float16)((u0.x - mu) * r); o[1] = (_Float16)((u0.y - mu) * r);
            o[2] = (_Float16)((u0.z - mu) * r); o[3] = (_Float16)((u0.w - mu) * r);
            o[4] = (_Float16)((u1.x - mu) * r); o[5] = (_Float16)((u1.y - mu) * r);
            o[6] = (_Float16)((u1.z - mu) * r); o[7] = (_Float16)((u1.w - mu) * r);
            qr[ln + 64 * j] = o;
        }
    } else {
        const int p = b - NLNB;                  // 0..1023
        float acc = 0.0f;
        const float4* w4 = (const float4*)w;
        for (unsigned i = (unsigned)p * 256u + t; i < 4194304u; i += 262144u) {
            float4 v = w4[i];                    // 16 iterations
            acc += (fabsf(v.x) + fabsf(v.y)) + (fabsf(v.z) + fabsf(v.w));
        }
        __shared__ float shw[4];
#pragma unroll
        for (int o = 32; o > 0; o >>= 1) acc += __shfl_down(acc, o, 64);
        if ((t & 63) == 0) shw[t >> 6] = acc;
        __syncthreads();
        if (t == 0) wpart[p] = (shw[0] + shw[1]) + (shw[2] + shw[3]);
    }
}

// ---------------- K2: reduce partials, ternarize W to f16 -------------------
__global__ __launch_bounds__(256) void ternW_k(
    const float* __restrict__ w, const float* __restrict__ wpart,
    float* __restrict__ sc, _Float16* __restrict__ q) {
    const int t = threadIdx.x;
    __shared__ float sh[4];
    float4 p = ((const float4*)wpart)[t];        // 256 threads cover 1024 partials
    float acc = (p.x + p.y) + (p.z + p.w);
#pragma unroll
    for (int o = 32; o > 0; o >>= 1) acc += __shfl_down(acc, o, 64);
    if ((t & 63) == 0) sh[t >> 6] = acc;
    __syncthreads();
    const float wg = ((sh[0] + sh[1]) + (sh[2] + sh[3])) * (1.0f / W_ELEMS);
    if (blockIdx.x == 0 && t == 0) sc[0] = wg;   // for GEMM epilogue
    const float invw = 1.0f / (wg + 1e-7f);
    for (unsigned i = blockIdx.x * 256u + t; i < 4194304u; i += 262144u) {
        float4 v = ((const float4*)w)[i];        // 16 iterations (1024 blocks)
        f16x4 o;
        o.x = (_Float16)fminf(fmaxf(rintf(v.x * invw), -1.0f), 1.0f);
        o.y = (_Float16)fminf(fmaxf(rintf(v.y * invw), -1.0f), 1.0f);
        o.z = (_Float16)fminf(fmaxf(rintf(v.z * invw), -1.0f), 1.0f);
        o.w = (_Float16)fminf(fmaxf(rintf(v.w * invw), -1.0f), 1.0f);
        ((f16x4*)q)[i] = o;
    }
}

// ---------------- K3: deep-pipelined dual GEMM + SiLU gate ------------------
__device__ __forceinline__ void ld16(const _Float16* g, _Float16* l) {
    __builtin_amdgcn_global_load_lds(
        (const __attribute__((address_space(1))) unsigned int*)g,
        (__attribute__((address_space(3))) unsigned int*)l, 16, 0, 0);
}

// LDS map (f16 elems): A buf0 [0,16384) buf1 [16384,32768);
//                      B buf0 [32768,49152) buf1 [49152,65536).
// B rows 0..127 = W rows n0..n0+127 (h); rows 128..255 = n0+4096.. (g).
// Swizzle: logical (row, 16B-granule g) stored at granule g ^ (row&7);
// staging keeps LDS linear and pre-swizzles the GLOBAL source column.
//
// Free-run schedule: per K-tile, phases (h,k0)(h,k1) | BARRIER-1 | (g,k0)
// (g,k1) | BARRIER-2. BARRIER-1 = VMC(4) [retire Bg(t)] + s_barrier: the only
// cross-wave RAW inside a tile (Bg rows are staged by all 8 waves). BARRIER-2
// = VMC(2) [retire Bh/A(t+1), keep Bg(t+1) in flight] + s_barrier: ends all
// reads of buf[p] before tile t+1 stages over it, and publishes Bh/A(t+1).
// No lgkmcnt drains: compiler emits precise lgkmcnt(N) for ds->MFMA deps.
// sched_barrier(0) after each barrier pins compile-time order (rule #18).

#define BAR    __builtin_amdgcn_s_barrier()
#define SCHED0 __builtin_amdgcn_sched_barrier(0)
#define VMC(n) asm volatile("s_waitcnt vmcnt(" #n ")" ::: "memory")
#define PRIO1  __builtin_amdgcn_s_setprio(1)
#define PRIO0  __builtin_amdgcn_s_setprio(0)

#define MFMA16(AARR, ACC)                                                 \
    _Pragma("unroll") for (int mi = 0; mi < 4; ++mi)                      \
    _Pragma("unroll") for (int ni = 0; ni < 4; ++ni)                      \
        ACC[mi][ni] = __builtin_amdgcn_mfma_f32_16x16x32_f16(             \
            AARR[mi], b[ni], ACC[mi][ni], 0, 0, 0);

#define DSA(AARR, AOFF)                                                   \
    _Pragma("unroll") for (int i = 0; i < 4; ++i)                         \
        AARR[i] = *(const f16x8*)(Ac + (AOFF) + (i << 10));

#define DSB(BOFF_)                                                        \
    _Pragma("unroll") for (int i = 0; i < 4; ++i)                         \
        b[i] = *(const f16x8*)(Bc + (BOFF_) + (i << 10));

__global__ __launch_bounds__(512, 2) void gemm_glu_k(
    const _Float16* __restrict__ Aq, const _Float16* __restrict__ Wq,
    const float* __restrict__ sc, float* __restrict__ out) {

    __shared__ __align__(16) _Float16 sm[65536];   // 128 KB

    const int tid  = threadIdx.x;
    const int wave = tid >> 6;
    const int lane = tid & 63;

    // bijective XCD swizzle (1024 % 8 == 0)
    const int swz = ((blockIdx.x & 7) << 7) + (blockIdx.x >> 3);
    const int m0 = (swz >> 5) << 8;   // tile row * 256
    const int n0 = (swz & 31) << 7;   // tile out-col * 128

    // --- staging addresses (global source pre-swizzled, LDS dest linear) ---
    const int rs = (wave << 3) + (lane >> 3);                  // row in 64-row stripe
    const int kc = (((lane & 7) ^ ((lane >> 3) & 7)) << 3);    // swizzled col
    const _Float16* pa = Aq + (size_t)(m0 + rs) * DIMIN + kc;
    const _Float16* pb = Wq + (size_t)(n0 + rs) * DIMIN + kc;

    // --- fragment read offsets (swizzled) ---
    const int fr   = lane & 15;
    const int quad = lane >> 4;
    const int xr   = fr & 7;
    const int wm = (wave >> 1) << 6;   // 0,64,128,192
    const int wn = (wave & 1) << 6;    // 0,64
    const int a0off = (wm + fr) * 64 + ((quad ^ xr) << 3);         // k-slice 0
    const int a1off = (wm + fr) * 64 + (((quad + 4) ^ xr) << 3);   // k-slice 1
    const int b0off = (wn + fr) * 64 + ((quad ^ xr) << 3);
    const int b1off = (wn + fr) * 64 + (((quad + 4) ^ xr) << 3);

    const float s = sc[0];             // w_gamma (uniform scalar load, early)

    f32x4 z = {0.0f, 0.0f, 0.0f, 0.0f};
    f32x4 acc_h[4][4], acc_g[4][4];
#pragma unroll
    for (int i = 0; i < 4; ++i)
#pragma unroll
        for (int j = 0; j < 4; ++j) { acc_h[i][j] = z; acc_g[i][j] = z; }

    // ---- prologue: stage tile 0 into buf0 (order Bh, A, Bg) ----
    {
        _Float16* dA = sm + (wave << 9);
        _Float16* dB = dA + 32768;
        ld16(pb,           dB);            // Bh0
        ld16(pb + 131072,  dB + 4096);     // Bh1
        ld16(pa,           dA);            // A0
        ld16(pa + 131072,  dA + 4096);     // A1
        ld16(pa + 262144,  dA + 8192);     // A2
        ld16(pa + 393216,  dA + 12288);    // A3
        ld16(pb + 8388608, dB + 8192);     // Bg0
        ld16(pb + 8519680, dB + 12288);    // Bg1
        pa += 64; pb += 64;
    }
    VMC(2);            // Bh+A of tile 0 landed; Bg(0) still in flight
    BAR; SCHED0;

    f16x8 a0[4], a1[4], b[4];
    for (int t = 0; t < 31; ++t) {         // steady state: stages tile t+1
        const _Float16* Ac = sm + ((t & 1) << 14);
        const _Float16* Bc = Ac + 32768;
        _Float16* dA = sm + (((t + 1) & 1) << 14) + (wave << 9);
        _Float16* dB = dA + 32768;

        // ---- P0: (h, k0) ----
        DSA(a0, a0off); DSB(b0off);
        ld16(pb,          dB);             // Bh0 (t+1)
        ld16(pb + 131072, dB + 4096);      // Bh1 (t+1)
        PRIO1; MFMA16(a0, acc_h); PRIO0;

        // ---- P1: (h, k1) ----
        DSA(a1, a1off); DSB(b1off);
        ld16(pa,          dA);             // A0 (t+1)
        ld16(pa + 131072, dA + 4096);      // A1 (t+1)
        PRIO1; MFMA16(a1, acc_h); PRIO0;

        VMC(4);                            // Bg(t) staged (cross-wave RAW)
        BAR; SCHED0;

        // ---- P2: (g, k0) -- reuse a0 ----
        DSB(8192 + b0off);
        ld16(pa + 262144, dA + 8192);      // A2 (t+1)
        ld16(pa + 393216, dA + 12288);     // A3 (t+1)
        PRIO1; MFMA16(a0, acc_g); PRIO0;

        // ---- P3: (g, k1) -- reuse a1 ----
        DSB(8192 + b1off);
        ld16(pb + 8388608, dB + 8192);     // Bg0 (t+1)
        ld16(pb + 8519680, dB + 12288);    // Bg1 (t+1)
        PRIO1; MFMA16(a1, acc_g); PRIO0;

        VMC(2);                            // reads(t) done; Bh/A(t+1) staged
        BAR; SCHED0;

        pa += 64; pb += 64;
    }

    // ---- tail tile (t = 31, buf 1, no staging) ----
    {
        const _Float16* Ac = sm + 16384;
        const _Float16* Bc = Ac + 32768;

        DSA(a0, a0off); DSB(b0off);
        PRIO1; MFMA16(a0, acc_h); PRIO0;

        DSA(a1, a1off); DSB(b1off);
        PRIO1; MFMA16(a1, acc_h); PRIO0;

        VMC(0);                            // drain Bg(31)
        BAR; SCHED0;

        DSB(8192 + b0off);
        PRIO1; MFMA16(a0, acc_g); PRIO0;

        DSB(8192 + b1off);
        PRIO1; MFMA16(a1, acc_g); PRIO0;
    }

    // ---- epilogue: GLU combine + store ----
    const int er = quad << 2;          // C/D: col = lane&15, row = quad*4 + r
#pragma unroll
    for (int mi = 0; mi < 4; ++mi)
#pragma unroll
        for (int ni = 0; ni < 4; ++ni)
#pragma unroll
            for (int r = 0; r < 4; ++r) {
                const int m = m0 + wm + (mi << 4) + er + r;
                const int n = n0 + wn + (ni << 4) + fr;
                const float h = acc_h[mi][ni][r] * s;
                const float g = acc_g[mi][ni][r] * s;
                out[(size_t)m * NOUT + n] = h * g / (1.0f + __expf(-g));
            }
}

// ---------------------------------------------------------------------------
extern "C" void kernel_launch(void* const* d_in, const int* in_sizes, int n_in,
                              void* d_out, int out_size, void* d_ws, size_t ws_size,
                              hipStream_t stream) {
    const float* x = (const float*)d_in[0];
    const float* w = (const float*)d_in[1];
    float* out = (float*)d_out;   // reference output dtype is float32

    char* ws = (char*)d_ws;
    float* sc    = (float*)ws;                                // [0] = wg
    float* wpart = (float*)(ws + 4096);                       // 1024 partials
    _Float16* qA = (_Float16*)(ws + 16384);                   // 32 MB normed f16
    _Float16* wB = (_Float16*)(ws + 16384 + 33554432);        // 32 MB ternary f16

    ln_wsum_k<<<NLNB + NPART, 256, 0, stream>>>(x, w, qA, wpart);
    ternW_k<<<NPART, 256, 0, stream>>>(w, wpart, sc, wB);

    gemm_glu_k<<<dim3(1024), dim3(512), 0, stream>>>(qA, wB, sc, out);
}